// Round 6
// baseline (254.958 us; speedup 1.0000x reference)
//
#include <hip/hip_runtime.h>
#include <hip/hip_bf16.h>

// Problem constants
#define TT   512
#define DD   64
#define NWK  4
#define STP  16
#define NPJ  15          // others per w
#define NBLK 60          // NWK * NPJ
#define TROWS 304        // diag-pair rows per transformed cost matrix
#define TSLOT (TROWS * TT)   // floats per transformed cost matrix
// u-domain scale: u = R / (gamma * ln2), gamma = 5
#define CSCALE 0.2885390081777927f
#define USCALE 3.4657359027997265f   // gamma * ln2
#define BIGC   2.885390081777927e8f  // 1e9 * CSCALE

// XOR swizzle for k-major LDS (stride 128): bank = (r ^ ((k>>2 &7)<<2)) % 32
#define SWZ(k) (((((k) >> 2) & 7)) << 2)

// ---------------------------------------------------------------------------
// Kernel 1: cost matrices in DIAGONAL-MAJOR pre-skewed layout:
//   element (r, c) -> u = r + ((c%128)>>1);  T2[u>>1][(c>>1)*4 + (u&1)*2 + (c&1)]
// This makes the DP kernel's skewed consumption a fully-coalesced float4 load.
// 128x128 tile per block, 8x8 register tile, swizzled k-major LDS. grid (4,4,n).
// ---------------------------------------------------------------------------
__global__ __launch_bounds__(256, 1) void cost_kernel(const float* __restrict__ data,
                                                      const int* __restrict__ lens,
                                                      float* __restrict__ costT, int base) {
  int blk = base + blockIdx.z;
  int w = blk / NPJ, j = blk - w * NPJ;
  int la = lens[w * STP];
  int lb = lens[w * STP + 1 + j];
  int ti = blockIdx.y, tj = blockIdx.x;
  if (ti * 128 >= la || tj * 128 >= lb) return;

  __shared__ float As[DD][128];   // swizzled k-major
  __shared__ float Bs[DD][128];
  __shared__ float a2[128], b2[128];

  const float* A = data + ((size_t)(w * STP) * TT + (size_t)ti * 128) * DD;
  const float* B = data + ((size_t)(w * STP + 1 + j) * TT + (size_t)tj * 128) * DD;
  int t = threadIdx.x;

  #pragma unroll
  for (int i = 0; i < 8; ++i) {
    int f = t + i * 256;          // float4 id in [0,2048): fully coalesced
    int r = f >> 4;               // row
    int k0 = (f & 15) << 2;       // k offset {0,4,...,60}
    int cs = r ^ SWZ(k0);         // swizzled col (same for k0..k0+3)
    float4 va = *(const float4*)(A + r * DD + k0);
    As[k0 + 0][cs] = va.x; As[k0 + 1][cs] = va.y;
    As[k0 + 2][cs] = va.z; As[k0 + 3][cs] = va.w;
    float4 vb = *(const float4*)(B + r * DD + k0);
    Bs[k0 + 0][cs] = vb.x; Bs[k0 + 1][cs] = vb.y;
    Bs[k0 + 2][cs] = vb.z; Bs[k0 + 3][cs] = vb.w;
  }
  __syncthreads();
  if (t < 128) {
    float s = 0.f;
    #pragma unroll 8
    for (int k = 0; k < DD; ++k) { float x = As[k][t ^ SWZ(k)]; s += x * x; }
    a2[t] = s;
  } else {
    int u = t - 128;
    float s = 0.f;
    #pragma unroll 8
    for (int k = 0; k < DD; ++k) { float x = Bs[k][u ^ SWZ(k)]; s += x * x; }
    b2[u] = s;
  }
  __syncthreads();

  int r0 = (t >> 4) << 2;   // {0,4,...,60}
  int c0 = (t & 15) << 2;   // {0,4,...,60}
  float acc[8][8];
  #pragma unroll
  for (int i = 0; i < 8; ++i)
    #pragma unroll
    for (int q = 0; q < 8; ++q) acc[i][q] = 0.f;

  float4 aL = *(const float4*)&As[0][r0];
  float4 aH = *(const float4*)&As[0][r0 + 64];
  float4 bL = *(const float4*)&Bs[0][c0];
  float4 bH = *(const float4*)&Bs[0][c0 + 64];

  #pragma unroll 4
  for (int k = 0; k < DD; ++k) {
    int kn = (k + 1) & 63;            // wrap: k=63 reloads k=0 (unused)
    int sw = SWZ(kn);
    float4 naL = *(const float4*)&As[kn][r0 ^ sw];
    float4 naH = *(const float4*)&As[kn][(r0 + 64) ^ sw];
    float4 nbL = *(const float4*)&Bs[kn][c0 ^ sw];
    float4 nbH = *(const float4*)&Bs[kn][(c0 + 64) ^ sw];
    float a[8] = {aL.x, aL.y, aL.z, aL.w, aH.x, aH.y, aH.z, aH.w};
    float b[8] = {bL.x, bL.y, bL.z, bL.w, bH.x, bH.y, bH.z, bH.w};
    #pragma unroll
    for (int i = 0; i < 8; ++i)
      #pragma unroll
      for (int q = 0; q < 8; ++q)
        acc[i][q] += a[i] * b[q];
    aL = naL; aH = naH; bL = nbL; bH = nbH;
  }

  // Epilogue: write diag-major pre-skewed. Pair index P = c>>1; skew = P%64.
  float* Tb = costT + (size_t)blockIdx.z * TSLOT;
  int ph = c0 >> 1;                 // {0,2,...,30}: within-slab pair base
  int pbase = tj * 64 + ph;         // global pair index base for q=0..1 cols
  #pragma unroll
  for (int i = 0; i < 8; ++i) {
    int rr = (i < 4) ? (r0 + i) : (r0 + 60 + i);
    int row = ti * 128 + rr;
    float ar = a2[rr];
    // 4 col-pairs: (+0), (+1), (+32), (+33) with skews ph, ph+1, ph+32, ph+33
    {
      int u = row + ph;
      float2 o = { (ar + b2[c0 + 0] - 2.f * acc[i][0]) * CSCALE,
                   (ar + b2[c0 + 1] - 2.f * acc[i][1]) * CSCALE };
      *(float2*)(Tb + (size_t)(u >> 1) * TT + (pbase + 0) * 4 + (u & 1) * 2) = o;
    }
    {
      int u = row + ph + 1;
      float2 o = { (ar + b2[c0 + 2] - 2.f * acc[i][2]) * CSCALE,
                   (ar + b2[c0 + 3] - 2.f * acc[i][3]) * CSCALE };
      *(float2*)(Tb + (size_t)(u >> 1) * TT + (pbase + 1) * 4 + (u & 1) * 2) = o;
    }
    {
      int u = row + ph + 32;
      float2 o = { (ar + b2[c0 + 64] - 2.f * acc[i][4]) * CSCALE,
                   (ar + b2[c0 + 65] - 2.f * acc[i][5]) * CSCALE };
      *(float2*)(Tb + (size_t)(u >> 1) * TT + (pbase + 32) * 4 + (u & 1) * 2) = o;
    }
    {
      int u = row + ph + 33;
      float2 o = { (ar + b2[c0 + 66] - 2.f * acc[i][6]) * CSCALE,
                   (ar + b2[c0 + 67] - 2.f * acc[i][7]) * CSCALE };
      *(float2*)(Tb + (size_t)(u >> 1) * TT + (pbase + 33) * 4 + (u & 1) * 2) = o;
    }
  }
}

// ---------------------------------------------------------------------------
// Soft-DTW DP cell in u-units: u = dc + min - log2(1 + 2^(min-med) + 2^(min-max))
// ---------------------------------------------------------------------------
__device__ __forceinline__ float dpcell(float dc, float a, float b, float c) {
  float mn = fminf(fminf(a, b), c);
  float mx = fmaxf(fmaxf(a, b), c);
  float md = __builtin_amdgcn_fmed3f(a, b, c);
  float e = 1.0f + __builtin_amdgcn_exp2f(mn - md) + __builtin_amdgcn_exp2f(mn - mx);
  return dc + mn - __builtin_amdgcn_logf(e);
}

// one DP row-step: k in [0,8), consumes cur[k>>1] components (k&1 selects half)
#define DPSTEP(kk, gg)                                                        \
  {                                                                           \
    int r = 8 * (gg) + (kk) - ln;                                             \
    float dx = ((kk) & 1) ? cur[(kk) >> 1].z : cur[(kk) >> 1].x;              \
    float dy = ((kk) & 1) ? cur[(kk) >> 1].w : cur[(kk) >> 1].y;              \
    if ((unsigned)r < 512u) {                                                 \
      float v0 = dpcell(dx, NLd, U0, NL);                                     \
      float v1 = dpcell(dy, U0, U1, v0);                                      \
      if (isT & (r == rt)) res = par ? v1 : v0;                               \
      NLd = NL; U0 = v0; U1 = v1; v1s = v1;                                   \
      if (wr63) {                                                             \
        bufB[q][r] = v1;                                                      \
        if ((r & 7) == 7) {                                                   \
          asm volatile("s_waitcnt lgkmcnt(0)" ::: "memory");  /* LDS-only release */ \
          *(volatile int*)&flags[q] = r + 1;                                  \
        }                                                                     \
      }                                                                       \
    }                                                                         \
    float nb = __shfl_up(v1s, 1);                                             \
    if (ln == 0) nb = (q == 0) ? BIGC : bb[kk];                               \
    NL = nb;                                                                  \
  }

#define DPGROUP(gg)                                                           \
  {                                                                           \
    nxt[0] = *(const float4*)(Tp + (size_t)(4 * (gg) + 4) * TT);              \
    nxt[1] = *(const float4*)(Tp + (size_t)(4 * (gg) + 5) * TT);              \
    nxt[2] = *(const float4*)(Tp + (size_t)(4 * (gg) + 6) * TT);              \
    nxt[3] = *(const float4*)(Tp + (size_t)(4 * (gg) + 7) * TT);              \
    __builtin_amdgcn_sched_barrier(0);   /* pin loads above the poll */       \
    if (q > 0) {                                                              \
      int need = 8 * (gg) + 9; if (need > la) need = la;                      \
      while (*(volatile int*)&flags[q - 1] < need) __builtin_amdgcn_s_sleep(1); \
      asm volatile("" ::: "memory");     /* compiler acquire; no vmcnt drain */ \
      bb[0] = bufB[q - 1][8 * (gg) + 1]; bb[1] = bufB[q - 1][8 * (gg) + 2];   \
      bb[2] = bufB[q - 1][8 * (gg) + 3]; bb[3] = bufB[q - 1][8 * (gg) + 4];   \
      bb[4] = bufB[q - 1][8 * (gg) + 5]; bb[5] = bufB[q - 1][8 * (gg) + 6];   \
      bb[6] = bufB[q - 1][8 * (gg) + 7]; bb[7] = bufB[q - 1][8 * (gg) + 8];   \
    }                                                                         \
    DPSTEP(0, gg) DPSTEP(1, gg) DPSTEP(2, gg) DPSTEP(3, gg)                   \
    DPSTEP(4, gg) DPSTEP(5, gg) DPSTEP(6, gg) DPSTEP(7, gg)                   \
    cur[0] = nxt[0]; cur[1] = nxt[1]; cur[2] = nxt[2]; cur[3] = nxt[3];       \
  }

// ---------------------------------------------------------------------------
// Kernel 2: fused DP (blocks [0,ndp)) + gram (blocks [ndp, ndp+121)).
// DP: barrier-free systolic pipeline over diag-major cost. 4 waves; wave q owns
// cols [128q,128q+128); lane owns 2 cols with 1-row/lane skew (shfl boundary);
// wave->wave via write-once LDS column + lgkm-only spin flags. Cost loads are
// fully coalesced float4 (one per 2 rows), prefetched one group ahead.
// waves_per_eu(1,1): pin register budget so the prefetch stays resident.
// ---------------------------------------------------------------------------
__global__ __launch_bounds__(256, 1) __attribute__((amdgpu_waves_per_eu(1, 1)))
void dp_gram_kernel(const float* __restrict__ costT,
                    const int* __restrict__ lens,
                    const float* __restrict__ data,
                    float* __restrict__ sdt,
                    float* __restrict__ gram,
                    int base, int ndp) {
  int bid = blockIdx.x;

  if (bid >= ndp) {
    // ---------------- gram path: 44x44 Gram over K = 32768 ----------------
    __shared__ float red[4][16];
    int g = bid - ndp;
    int bx = g / 11, by = g - bx * 11;
    int t = threadIdx.x;
    const float* Ar[4]; const float* Br[4];
    #pragma unroll
    for (int a = 0; a < 4; ++a) {
      int gx = bx * 4 + a;
      Ar[a] = data + (size_t)((gx / 11) * STP + gx % 11) * (TT * DD);
      int gy = by * 4 + a;
      Br[a] = data + (size_t)((gy / 11) * STP + gy % 11) * (TT * DD);
    }
    float acc[4][4];
    #pragma unroll
    for (int a = 0; a < 4; ++a)
      #pragma unroll
      for (int b = 0; b < 4; ++b) acc[a][b] = 0.f;
    for (int k = t * 4; k < TT * DD; k += 1024) {
      float4 av[4], bv[4];
      #pragma unroll
      for (int a = 0; a < 4; ++a) av[a] = *(const float4*)(Ar[a] + k);
      #pragma unroll
      for (int b = 0; b < 4; ++b) bv[b] = *(const float4*)(Br[b] + k);
      #pragma unroll
      for (int a = 0; a < 4; ++a)
        #pragma unroll
        for (int b = 0; b < 4; ++b)
          acc[a][b] += av[a].x * bv[b].x + av[a].y * bv[b].y +
                       av[a].z * bv[b].z + av[a].w * bv[b].w;
    }
    int wave = t >> 6, lane = t & 63;
    #pragma unroll
    for (int a = 0; a < 4; ++a)
      #pragma unroll
      for (int b = 0; b < 4; ++b) {
        float v = acc[a][b];
        for (int off = 32; off > 0; off >>= 1) v += __shfl_down(v, off);
        if (lane == 0) red[wave][a * 4 + b] = v;
      }
    __syncthreads();
    if (t < 16) {
      float v = red[0][t] + red[1][t] + red[2][t] + red[3][t];
      int a = t >> 2, b = t & 3;
      gram[(size_t)(bx * 4 + a) * 44 + by * 4 + b] = v;
    }
    return;
  }

  // -------------------------- DP path --------------------------
  __shared__ float bufB[3][640];   // boundary column per wave (write-once)
  __shared__ int flags[4];

  if (threadIdx.x < 4) flags[threadIdx.x] = 0;
  __syncthreads();

  int blk = base + bid;
  int w = blk / NPJ, j = blk - w * NPJ;
  int la = lens[w * STP];
  int lb = lens[w * STP + 1 + j];

  int q = threadIdx.x >> 6, ln = threadIdx.x & 63;
  // coalesced: lane's float4 column in the diag-major matrix
  const float* Tp = costT + (size_t)bid * TSLOT + (q * 64 + ln) * 4;
  bool wr63 = (q < 3) & (ln == 63);

  // target cell (la-1, lb-1)
  int qt = (lb - 1) >> 7;
  int lt = ((lb - 1) & 127) >> 1;
  int par = (lb - 1) & 1;
  int rt = la - 1;
  bool isT = (q == qt) && (ln == lt);

  float U0 = BIGC, U1 = BIGC;          // own cols, previous row
  float NL = BIGC;                     // left neighbor value, current row
  float NLd = (q == 0 && ln == 0) ? 0.0f : BIGC;  // left-diag (prev row)
  float v1s = BIGC;                    // last computed right-col value
  float res = 0.0f;
  float bb[8];

  int ngrp = (la + 70) >> 3;

  float4 cur[4], nxt[4];
  cur[0] = *(const float4*)(Tp + (size_t)0 * TT);
  cur[1] = *(const float4*)(Tp + (size_t)1 * TT);
  cur[2] = *(const float4*)(Tp + (size_t)2 * TT);
  cur[3] = *(const float4*)(Tp + (size_t)3 * TT);

  for (int g = 0; g < ngrp; ++g) {
    DPGROUP(g)
  }
  if (wr63) {
    asm volatile("s_waitcnt lgkmcnt(0)" ::: "memory");
    *(volatile int*)&flags[q] = 512;   // release any remaining pollers
  }
  if (isT) sdt[blk] = res * USCALE;
}

// ---------------------------------------------------------------------------
// Kernel 4: final combine. block 640 = 10 waves; waves 0..8: one MMD pair each;
// wave 9: triplet losses; thread 0 writes the scalar.
// ---------------------------------------------------------------------------
__global__ __launch_bounds__(640) void final_kernel(const float* __restrict__ sdt,
                                                    const int* __restrict__ lens,
                                                    const float* __restrict__ gram,
                                                    float* __restrict__ out) {
  __shared__ float partial[16];
  int t = threadIdx.x, wave = t >> 6, lane = t & 63;
  if (wave < 9) {
    const int piA[9] = {0, 0, 0, 1, 1, 2, 2, 3, 3};
    const int pjA[9] = {1, 2, 3, 2, 3, 1, 3, 1, 2};
    int P = piA[wave], Q = pjA[wave];
    float s1 = 0.f;
    for (int c = lane; c < 484; c += 64) {
      int i = c / 22, jj = c - (c / 22) * 22;
      int gi = (i < 11) ? P * 11 + i : Q * 11 + (i - 11);
      int gj = (jj < 11) ? P * 11 + jj : Q * 11 + (jj - 11);
      s1 += gram[gi * 44 + gi] + gram[gj * 44 + gj] - 2.f * gram[gi * 44 + gj];
    }
    for (int off = 32; off > 0; off >>= 1) s1 += __shfl_down(s1, off);
    s1 = __shfl(s1, 0);
    float bw = s1 / 462.0f * 0.25f;     // /(ns^2-ns) then / KMUL^(KNUM//2)=4
    float inv[5];
    float b = bw;
    #pragma unroll
    for (int qq = 0; qq < 5; ++qq) { inv[qq] = -1.0f / b; b *= 2.0f; }
    float s2 = 0.f;
    for (int c = lane; c < 484; c += 64) {
      int i = c / 22, jj = c - (c / 22) * 22;
      int gi = (i < 11) ? P * 11 + i : Q * 11 + (i - 11);
      int gj = (jj < 11) ? P * 11 + jj : Q * 11 + (jj - 11);
      float l2 = gram[gi * 44 + gi] + gram[gj * 44 + gj] - 2.f * gram[gi * 44 + gj];
      float kk = 0.f;
      #pragma unroll
      for (int qq = 0; qq < 5; ++qq) kk += __expf(l2 * inv[qq]);
      float sgn = ((i < 11) == (jj < 11)) ? 1.0f : -1.0f;
      s2 += sgn * kk;
    }
    for (int off = 32; off > 0; off >>= 1) s2 += __shfl_down(s2, off);
    if (lane == 0) partial[wave] = s2 / 121.0f;
  } else {
    float term = 0.f;
    if (wave == 9 && lane < 4) {
      int w = lane;
      float L0 = (float)lens[w * STP];
      float dist[15];
      for (int qq = 0; qq < 15; ++qq)
        dist[qq] = sdt[w * NPJ + qq] / (L0 + (float)lens[w * STP + 1 + qq]);
      float ca = 0.f, cb = 0.f;
      for (int a = 0; a < 6; ++a) ca += dist[a];
      ca *= (1.0f / 6.0f);
      for (int bq = 6; bq < 11; ++bq) cb += dist[bq];
      cb *= (1.0f / 5.0f);
      float lksum = 0.f; int nz = 0;
      for (int a = 0; a < 6; ++a)
        for (int bq = 6; bq < 15; ++bq) {
          float x = dist[a] + 1.0f - dist[bq];   // MARGIN = 1.0
          if (x > 0.f) { lksum += x; nz += 1; }
        }
      float intra = 0.f;
      for (int a = 0; a < 6; ++a) intra += dist[a] - ca;
      float inter = fmaxf(0.f, 1.0f - fabsf(ca - cb));  // BETA = 1.0
      term = lksum / (float)(nz + 1) + intra * 0.1f + inter * 0.1f;  // P=R=0.1
    }
    if (wave == 9) {
      term += __shfl_down(term, 1);
      term += __shfl_down(term, 2);
      if (lane == 0) partial[9] = term * 0.25f;   // mean over NW=4
    }
  }
  __syncthreads();
  if (t == 0) {
    float mx = 0.0f;                               // zero-pad in the max
    for (int p = 0; p < 9; ++p) mx = fmaxf(mx, partial[p]);
    out[0] = partial[9] + 0.01f * mx;              // ALPHA = 0.01
  }
}

// ---------------------------------------------------------------------------
extern "C" void kernel_launch(void* const* d_in, const int* in_sizes, int n_in,
                              void* d_out, int out_size, void* d_ws, size_t ws_size,
                              hipStream_t stream) {
  const float* data = (const float*)d_in[0];
  const int* lens = (const int*)d_in[1];
  float* out = (float*)d_out;

  float* sdtb  = (float*)d_ws;                      // 60 floats
  float* gramb = sdtb + 64;                         // 44*44 floats
  float* costb = (float*)((char*)d_ws + 8192);      // transformed cost chunks

  size_t avail = (ws_size > 8192) ? (ws_size - 8192) : 0;
  int chunk = (int)(avail / ((size_t)TSLOT * sizeof(float)));
  if (chunk < 1) chunk = 1;
  if (chunk > NBLK) chunk = NBLK;

  bool first = true;
  for (int base = 0; base < NBLK; base += chunk) {
    int n = NBLK - base;
    if (n > chunk) n = chunk;
    cost_kernel<<<dim3(4, 4, n), 256, 0, stream>>>(data, lens, costb, base);
    int extra = first ? 121 : 0;   // fuse gram onto otherwise-idle CUs
    dp_gram_kernel<<<n + extra, 256, 0, stream>>>(costb, lens, data, sdtb, gramb, base, n);
    first = false;
  }
  final_kernel<<<1, 640, 0, stream>>>(sdtb, lens, gramb, out);
}

// Round 8
// 240.833 us; speedup vs baseline: 1.0587x; 1.0587x over previous
//
#include <hip/hip_runtime.h>
#include <hip/hip_bf16.h>

// Problem constants
#define TT   512
#define DD   64
#define NWK  4
#define STP  16
#define NPJ  15          // others per w
#define NBLK 60          // NWK * NPJ
#define TROWS 304        // diag-pair rows per transformed cost matrix
#define TSLOT (TROWS * TT)   // floats per transformed cost matrix
// u-domain scale: u = R / (gamma * ln2), gamma = 5
#define CSCALE 0.2885390081777927f
#define USCALE 3.4657359027997265f   // gamma * ln2
#define BIGC   2.885390081777927e8f  // 1e9 * CSCALE

// XOR swizzle for k-major LDS (stride 128): bank = (r ^ ((k>>2 &7)<<2)) % 32
#define SWZ(k) (((((k) >> 2) & 7)) << 2)

// ---------------------------------------------------------------------------
// Kernel 1: cost matrices in DIAGONAL-MAJOR pre-skewed layout:
//   element (r, c) -> u = r + ((c%128)>>1);  T2[u>>1][(c>>1)*4 + (u&1)*2 + (c&1)]
// This makes the DP kernel's skewed consumption a fully-coalesced float4 load.
// 128x128 tile per block, 8x8 register tile, swizzled k-major LDS. grid (4,4,n).
// ---------------------------------------------------------------------------
__global__ __launch_bounds__(256, 1) void cost_kernel(const float* __restrict__ data,
                                                      const int* __restrict__ lens,
                                                      float* __restrict__ costT, int base) {
  int blk = base + blockIdx.z;
  int w = blk / NPJ, j = blk - w * NPJ;
  int la = lens[w * STP];
  int lb = lens[w * STP + 1 + j];
  int ti = blockIdx.y, tj = blockIdx.x;
  if (ti * 128 >= la || tj * 128 >= lb) return;

  __shared__ float As[DD][128];   // swizzled k-major
  __shared__ float Bs[DD][128];
  __shared__ float a2[128], b2[128];

  const float* A = data + ((size_t)(w * STP) * TT + (size_t)ti * 128) * DD;
  const float* B = data + ((size_t)(w * STP + 1 + j) * TT + (size_t)tj * 128) * DD;
  int t = threadIdx.x;

  #pragma unroll
  for (int i = 0; i < 8; ++i) {
    int f = t + i * 256;          // float4 id in [0,2048): fully coalesced
    int r = f >> 4;               // row
    int k0 = (f & 15) << 2;       // k offset {0,4,...,60}
    int cs = r ^ SWZ(k0);         // swizzled col (same for k0..k0+3)
    float4 va = *(const float4*)(A + r * DD + k0);
    As[k0 + 0][cs] = va.x; As[k0 + 1][cs] = va.y;
    As[k0 + 2][cs] = va.z; As[k0 + 3][cs] = va.w;
    float4 vb = *(const float4*)(B + r * DD + k0);
    Bs[k0 + 0][cs] = vb.x; Bs[k0 + 1][cs] = vb.y;
    Bs[k0 + 2][cs] = vb.z; Bs[k0 + 3][cs] = vb.w;
  }
  __syncthreads();
  if (t < 128) {
    float s = 0.f;
    #pragma unroll 8
    for (int k = 0; k < DD; ++k) { float x = As[k][t ^ SWZ(k)]; s += x * x; }
    a2[t] = s;
  } else {
    int u = t - 128;
    float s = 0.f;
    #pragma unroll 8
    for (int k = 0; k < DD; ++k) { float x = Bs[k][u ^ SWZ(k)]; s += x * x; }
    b2[u] = s;
  }
  __syncthreads();

  int r0 = (t >> 4) << 2;   // {0,4,...,60}
  int c0 = (t & 15) << 2;   // {0,4,...,60}
  float acc[8][8];
  #pragma unroll
  for (int i = 0; i < 8; ++i)
    #pragma unroll
    for (int q = 0; q < 8; ++q) acc[i][q] = 0.f;

  float4 aL = *(const float4*)&As[0][r0];
  float4 aH = *(const float4*)&As[0][r0 + 64];
  float4 bL = *(const float4*)&Bs[0][c0];
  float4 bH = *(const float4*)&Bs[0][c0 + 64];

  #pragma unroll 4
  for (int k = 0; k < DD; ++k) {
    int kn = (k + 1) & 63;            // wrap: k=63 reloads k=0 (unused)
    int sw = SWZ(kn);
    float4 naL = *(const float4*)&As[kn][r0 ^ sw];
    float4 naH = *(const float4*)&As[kn][(r0 + 64) ^ sw];
    float4 nbL = *(const float4*)&Bs[kn][c0 ^ sw];
    float4 nbH = *(const float4*)&Bs[kn][(c0 + 64) ^ sw];
    float a[8] = {aL.x, aL.y, aL.z, aL.w, aH.x, aH.y, aH.z, aH.w};
    float b[8] = {bL.x, bL.y, bL.z, bL.w, bH.x, bH.y, bH.z, bH.w};
    #pragma unroll
    for (int i = 0; i < 8; ++i)
      #pragma unroll
      for (int q = 0; q < 8; ++q)
        acc[i][q] += a[i] * b[q];
    aL = naL; aH = naH; bL = nbL; bH = nbH;
  }

  // Epilogue: write diag-major pre-skewed. Pair index P = c>>1; skew = P%64.
  float* Tb = costT + (size_t)blockIdx.z * TSLOT;
  int ph = c0 >> 1;                 // {0,2,...,30}: within-slab pair base
  int pbase = tj * 64 + ph;         // global pair index base for q=0..1 cols
  #pragma unroll
  for (int i = 0; i < 8; ++i) {
    int rr = (i < 4) ? (r0 + i) : (r0 + 60 + i);
    int row = ti * 128 + rr;
    float ar = a2[rr];
    {
      int u = row + ph;
      float2 o = { (ar + b2[c0 + 0] - 2.f * acc[i][0]) * CSCALE,
                   (ar + b2[c0 + 1] - 2.f * acc[i][1]) * CSCALE };
      *(float2*)(Tb + (size_t)(u >> 1) * TT + (pbase + 0) * 4 + (u & 1) * 2) = o;
    }
    {
      int u = row + ph + 1;
      float2 o = { (ar + b2[c0 + 2] - 2.f * acc[i][2]) * CSCALE,
                   (ar + b2[c0 + 3] - 2.f * acc[i][3]) * CSCALE };
      *(float2*)(Tb + (size_t)(u >> 1) * TT + (pbase + 1) * 4 + (u & 1) * 2) = o;
    }
    {
      int u = row + ph + 32;
      float2 o = { (ar + b2[c0 + 64] - 2.f * acc[i][4]) * CSCALE,
                   (ar + b2[c0 + 65] - 2.f * acc[i][5]) * CSCALE };
      *(float2*)(Tb + (size_t)(u >> 1) * TT + (pbase + 32) * 4 + (u & 1) * 2) = o;
    }
    {
      int u = row + ph + 33;
      float2 o = { (ar + b2[c0 + 66] - 2.f * acc[i][6]) * CSCALE,
                   (ar + b2[c0 + 67] - 2.f * acc[i][7]) * CSCALE };
      *(float2*)(Tb + (size_t)(u >> 1) * TT + (pbase + 33) * 4 + (u & 1) * 2) = o;
    }
  }
}

// ---------------------------------------------------------------------------
// Soft-DTW DP cell in u-units: u = dc + min - log2(1 + 2^(min-med) + 2^(min-max))
// ---------------------------------------------------------------------------
__device__ __forceinline__ float dpcell(float dc, float a, float b, float c) {
  float mn = fminf(fminf(a, b), c);
  float mx = fmaxf(fmaxf(a, b), c);
  float md = __builtin_amdgcn_fmed3f(a, b, c);
  float e = 1.0f + __builtin_amdgcn_exp2f(mn - md) + __builtin_amdgcn_exp2f(mn - mx);
  return dc + mn - __builtin_amdgcn_logf(e);
}

// lane-shift by 1 (wave_shr1 = 0x138): lane n gets lane n-1; lane 0 keeps old.
// Pure VALU (~4 cyc) — replaces ds_bpermute-based __shfl_up (~120 cyc).
__device__ __forceinline__ float shift_up1(float v) {
  return __int_as_float(__builtin_amdgcn_update_dpp(
      __float_as_int(v), __float_as_int(v), 0x138, 0xf, 0xf, false));
}

// issue 4 global_load_dwordx4 into B0..B3 for T-rows at PTR (B live until WAITC)
#define ISSUE(B0, B1, B2, B3, PTR)                                            \
  { const float* _pa = (PTR); const float* _pb = _pa + 2 * TT;                \
    asm volatile("global_load_dwordx4 %0, %4, off\n\t"                        \
                 "global_load_dwordx4 %1, %4, off offset:2048\n\t"            \
                 "global_load_dwordx4 %2, %5, off\n\t"                        \
                 "global_load_dwordx4 %3, %5, off offset:2048"                \
                 : "=&v"(B0), "=&v"(B1), "=&v"(B2), "=&v"(B3)                 \
                 : "v"(_pa), "v"(_pb)                                         \
                 : "memory"); }

// wait until <=4 vmem outstanding, then materialize the 16 loaded floats as
// NEW values data-dependent on the waitcnt. B0..B3 as inputs keep the load
// destination registers live (reserved) from ISSUE to here; outputs are
// early-clobber so the movs cannot overwrite unread inputs.
#define WAITC(B0, B1, B2, B3, o0, o1, o2, o3, o4, o5, o6, o7,                 \
              o8, o9, o10, o11, o12, o13, o14, o15)                           \
  asm volatile("s_waitcnt vmcnt(4)\n\t"                                       \
               "v_mov_b32 %0, %16\n\t"  "v_mov_b32 %1, %17\n\t"               \
               "v_mov_b32 %2, %18\n\t"  "v_mov_b32 %3, %19\n\t"               \
               "v_mov_b32 %4, %20\n\t"  "v_mov_b32 %5, %21\n\t"               \
               "v_mov_b32 %6, %22\n\t"  "v_mov_b32 %7, %23\n\t"               \
               "v_mov_b32 %8, %24\n\t"  "v_mov_b32 %9, %25\n\t"               \
               "v_mov_b32 %10, %26\n\t" "v_mov_b32 %11, %27\n\t"              \
               "v_mov_b32 %12, %28\n\t" "v_mov_b32 %13, %29\n\t"              \
               "v_mov_b32 %14, %30\n\t" "v_mov_b32 %15, %31"                  \
               : "=&v"(o0), "=&v"(o1), "=&v"(o2), "=&v"(o3),                  \
                 "=&v"(o4), "=&v"(o5), "=&v"(o6), "=&v"(o7),                  \
                 "=&v"(o8), "=&v"(o9), "=&v"(o10), "=&v"(o11),                \
                 "=&v"(o12), "=&v"(o13), "=&v"(o14), "=&v"(o15)               \
               : "v"(B0.x), "v"(B0.y), "v"(B0.z), "v"(B0.w),                  \
                 "v"(B1.x), "v"(B1.y), "v"(B1.z), "v"(B1.w),                  \
                 "v"(B2.x), "v"(B2.y), "v"(B2.z), "v"(B2.w),                  \
                 "v"(B3.x), "v"(B3.y), "v"(B3.z), "v"(B3.w)                   \
               : "memory");

// one DP row-step consuming already-materialized dx, dy
#define DPSTEP(dx, dy, kk, gg)                                                \
  {                                                                           \
    int r = 8 * (gg) + (kk) - ln;                                             \
    if ((unsigned)r < 512u) {                                                 \
      float v0 = dpcell(dx, NLd, U0, NL);                                     \
      float v1 = dpcell(dy, U0, U1, v0);                                      \
      if (isT & (r == rt)) res = par ? v1 : v0;                               \
      NLd = NL; U0 = v0; U1 = v1; v1s = v1;                                   \
      if (wr63) {                                                             \
        bufB[q][r] = v1;                                                      \
        if ((r & 7) == 7) {                                                   \
          asm volatile("s_waitcnt lgkmcnt(0)" ::: "memory");  /* LDS-only release */ \
          *(volatile int*)&flags[q] = r + 1;                                  \
        }                                                                     \
      }                                                                       \
    }                                                                         \
    float sh = shift_up1(v1s);                                                \
    NL = (ln == 0) ? ((q == 0) ? BIGC : bb[kk]) : sh;                         \
  }

#define DPGROUP(B0, B1, B2, B3, gg)                                           \
  {                                                                           \
    float o0, o1, o2, o3, o4, o5, o6, o7, o8, o9, o10, o11, o12, o13, o14, o15; \
    WAITC(B0, B1, B2, B3, o0, o1, o2, o3, o4, o5, o6, o7,                     \
          o8, o9, o10, o11, o12, o13, o14, o15)                               \
    if (q > 0) {                                                              \
      int need = 8 * (gg) + 9; if (need > la) need = la;                      \
      while (*(volatile int*)&flags[q - 1] < need) __builtin_amdgcn_s_sleep(1); \
      asm volatile("" ::: "memory");     /* compiler acquire; no vmcnt drain */ \
      bb[0] = bufB[q - 1][8 * (gg) + 1]; bb[1] = bufB[q - 1][8 * (gg) + 2];   \
      bb[2] = bufB[q - 1][8 * (gg) + 3]; bb[3] = bufB[q - 1][8 * (gg) + 4];   \
      bb[4] = bufB[q - 1][8 * (gg) + 5]; bb[5] = bufB[q - 1][8 * (gg) + 6];   \
      bb[6] = bufB[q - 1][8 * (gg) + 7]; bb[7] = bufB[q - 1][8 * (gg) + 8];   \
    }                                                                         \
    DPSTEP(o0, o1, 0, gg)   DPSTEP(o2, o3, 1, gg)                             \
    DPSTEP(o4, o5, 2, gg)   DPSTEP(o6, o7, 3, gg)                             \
    DPSTEP(o8, o9, 4, gg)   DPSTEP(o10, o11, 5, gg)                           \
    DPSTEP(o12, o13, 6, gg) DPSTEP(o14, o15, 7, gg)                           \
    ISSUE(B0, B1, B2, B3, Tp + (size_t)(4 * (gg) + 8) * TT)                   \
  }

// ---------------------------------------------------------------------------
// Kernel 2: fused DP (blocks [0,ndp)) + gram (blocks [ndp, ndp+121)).
// DP: barrier-free systolic pipeline over diag-major cost. 4 waves; wave q owns
// cols [128q,128q+128); lane owns 2 cols with 1-row/lane skew; lane boundary
// via DPP wave_shr1 (VALU, no LDS); wave boundary via write-once LDS column +
// lgkm-only spin flags. Cost loads double-buffered 2 groups deep with explicit
// vmcnt(4); load regs kept live via asm input liveness — compiler cannot sink.
// ---------------------------------------------------------------------------
__global__ __launch_bounds__(256) __attribute__((amdgpu_waves_per_eu(1, 4)))
void dp_gram_kernel(const float* __restrict__ costT,
                    const int* __restrict__ lens,
                    const float* __restrict__ data,
                    float* __restrict__ sdt,
                    float* __restrict__ gram,
                    int base, int ndp) {
  int bid = blockIdx.x;

  if (bid >= ndp) {
    // ---------------- gram path: 44x44 Gram over K = 32768 ----------------
    __shared__ float red[4][16];
    int g = bid - ndp;
    int bx = g / 11, by = g - bx * 11;
    int t = threadIdx.x;
    const float* Ar[4]; const float* Br[4];
    #pragma unroll
    for (int a = 0; a < 4; ++a) {
      int gx = bx * 4 + a;
      Ar[a] = data + (size_t)((gx / 11) * STP + gx % 11) * (TT * DD);
      int gy = by * 4 + a;
      Br[a] = data + (size_t)((gy / 11) * STP + gy % 11) * (TT * DD);
    }
    float acc[4][4];
    #pragma unroll
    for (int a = 0; a < 4; ++a)
      #pragma unroll
      for (int b = 0; b < 4; ++b) acc[a][b] = 0.f;
    for (int k = t * 4; k < TT * DD; k += 1024) {
      float4 av[4], bv[4];
      #pragma unroll
      for (int a = 0; a < 4; ++a) av[a] = *(const float4*)(Ar[a] + k);
      #pragma unroll
      for (int b = 0; b < 4; ++b) bv[b] = *(const float4*)(Br[b] + k);
      #pragma unroll
      for (int a = 0; a < 4; ++a)
        #pragma unroll
        for (int b = 0; b < 4; ++b)
          acc[a][b] += av[a].x * bv[b].x + av[a].y * bv[b].y +
                       av[a].z * bv[b].z + av[a].w * bv[b].w;
    }
    int wave = t >> 6, lane = t & 63;
    #pragma unroll
    for (int a = 0; a < 4; ++a)
      #pragma unroll
      for (int b = 0; b < 4; ++b) {
        float v = acc[a][b];
        for (int off = 32; off > 0; off >>= 1) v += __shfl_down(v, off);
        if (lane == 0) red[wave][a * 4 + b] = v;
      }
    __syncthreads();
    if (t < 16) {
      float v = red[0][t] + red[1][t] + red[2][t] + red[3][t];
      int a = t >> 2, b = t & 3;
      gram[(size_t)(bx * 4 + a) * 44 + by * 4 + b] = v;
    }
    return;
  }

  // -------------------------- DP path --------------------------
  __shared__ float bufB[3][640];   // boundary column per wave (write-once)
  __shared__ int flags[4];

  if (threadIdx.x < 4) flags[threadIdx.x] = 0;
  __syncthreads();

  int blk = base + bid;
  int w = blk / NPJ, j = blk - w * NPJ;
  int la = lens[w * STP];
  int lb = lens[w * STP + 1 + j];

  int q = threadIdx.x >> 6, ln = threadIdx.x & 63;
  // coalesced: lane's float4 column in the diag-major matrix
  const float* Tp = costT + (size_t)bid * TSLOT + (q * 64 + ln) * 4;
  bool wr63 = (q < 3) & (ln == 63);

  // target cell (la-1, lb-1)
  int qt = (lb - 1) >> 7;
  int lt = ((lb - 1) & 127) >> 1;
  int par = (lb - 1) & 1;
  int rt = la - 1;
  bool isT = (q == qt) && (ln == lt);

  float U0 = BIGC, U1 = BIGC;          // own cols, previous row
  float NL = BIGC;                     // left neighbor value, current row
  float NLd = (q == 0 && ln == 0) ? 0.0f : BIGC;  // left-diag (prev row)
  float v1s = BIGC;                    // last computed right-col value
  float res = 0.0f;
  float bb[8];

  int ngrp = (la + 70) >> 3;
  int ngrp2 = (ngrp + 1) & ~1;         // even (<= 72; T reads stay < 304 rows)

  float4 A0, A1, A2, A3, B0, B1, B2, B3;
  ISSUE(A0, A1, A2, A3, Tp)                        // group 0: T-rows 0..3
  ISSUE(B0, B1, B2, B3, Tp + (size_t)4 * TT)       // group 1: T-rows 4..7

  for (int g = 0; g < ngrp2; g += 2) {
    DPGROUP(A0, A1, A2, A3, g)
    DPGROUP(B0, B1, B2, B3, g + 1)
  }
  asm volatile("s_waitcnt vmcnt(0)" ::: "memory");  // drain pinned loads
  if (wr63) {
    asm volatile("s_waitcnt lgkmcnt(0)" ::: "memory");
    *(volatile int*)&flags[q] = 512;   // release any remaining pollers
  }
  if (isT) sdt[blk] = res * USCALE;
}

// ---------------------------------------------------------------------------
// Kernel 4: final combine. block 640 = 10 waves; waves 0..8: one MMD pair each;
// wave 9: triplet losses; thread 0 writes the scalar.
// ---------------------------------------------------------------------------
__global__ __launch_bounds__(640) void final_kernel(const float* __restrict__ sdt,
                                                    const int* __restrict__ lens,
                                                    const float* __restrict__ gram,
                                                    float* __restrict__ out) {
  __shared__ float partial[16];
  int t = threadIdx.x, wave = t >> 6, lane = t & 63;
  if (wave < 9) {
    const int piA[9] = {0, 0, 0, 1, 1, 2, 2, 3, 3};
    const int pjA[9] = {1, 2, 3, 2, 3, 1, 3, 1, 2};
    int P = piA[wave], Q = pjA[wave];
    float s1 = 0.f;
    for (int c = lane; c < 484; c += 64) {
      int i = c / 22, jj = c - (c / 22) * 22;
      int gi = (i < 11) ? P * 11 + i : Q * 11 + (i - 11);
      int gj = (jj < 11) ? P * 11 + jj : Q * 11 + (jj - 11);
      s1 += gram[gi * 44 + gi] + gram[gj * 44 + gj] - 2.f * gram[gi * 44 + gj];
    }
    for (int off = 32; off > 0; off >>= 1) s1 += __shfl_down(s1, off);
    s1 = __shfl(s1, 0);
    float bw = s1 / 462.0f * 0.25f;     // /(ns^2-ns) then / KMUL^(KNUM//2)=4
    float inv[5];
    float b = bw;
    #pragma unroll
    for (int qq = 0; qq < 5; ++qq) { inv[qq] = -1.0f / b; b *= 2.0f; }
    float s2 = 0.f;
    for (int c = lane; c < 484; c += 64) {
      int i = c / 22, jj = c - (c / 22) * 22;
      int gi = (i < 11) ? P * 11 + i : Q * 11 + (i - 11);
      int gj = (jj < 11) ? P * 11 + jj : Q * 11 + (jj - 11);
      float l2 = gram[gi * 44 + gi] + gram[gj * 44 + gj] - 2.f * gram[gi * 44 + gj];
      float kk = 0.f;
      #pragma unroll
      for (int qq = 0; qq < 5; ++qq) kk += __expf(l2 * inv[qq]);
      float sgn = ((i < 11) == (jj < 11)) ? 1.0f : -1.0f;
      s2 += sgn * kk;
    }
    for (int off = 32; off > 0; off >>= 1) s2 += __shfl_down(s2, off);
    if (lane == 0) partial[wave] = s2 / 121.0f;
  } else {
    float term = 0.f;
    if (wave == 9 && lane < 4) {
      int w = lane;
      float L0 = (float)lens[w * STP];
      float dist[15];
      for (int qq = 0; qq < 15; ++qq)
        dist[qq] = sdt[w * NPJ + qq] / (L0 + (float)lens[w * STP + 1 + qq]);
      float ca = 0.f, cb = 0.f;
      for (int a = 0; a < 6; ++a) ca += dist[a];
      ca *= (1.0f / 6.0f);
      for (int bq = 6; bq < 11; ++bq) cb += dist[bq];
      cb *= (1.0f / 5.0f);
      float lksum = 0.f; int nz = 0;
      for (int a = 0; a < 6; ++a)
        for (int bq = 6; bq < 15; ++bq) {
          float x = dist[a] + 1.0f - dist[bq];   // MARGIN = 1.0
          if (x > 0.f) { lksum += x; nz += 1; }
        }
      float intra = 0.f;
      for (int a = 0; a < 6; ++a) intra += dist[a] - ca;
      float inter = fmaxf(0.f, 1.0f - fabsf(ca - cb));  // BETA = 1.0
      term = lksum / (float)(nz + 1) + intra * 0.1f + inter * 0.1f;  // P=R=0.1
    }
    if (wave == 9) {
      term += __shfl_down(term, 1);
      term += __shfl_down(term, 2);
      if (lane == 0) partial[9] = term * 0.25f;   // mean over NW=4
    }
  }
  __syncthreads();
  if (t == 0) {
    float mx = 0.0f;                               // zero-pad in the max
    for (int p = 0; p < 9; ++p) mx = fmaxf(mx, partial[p]);
    out[0] = partial[9] + 0.01f * mx;              // ALPHA = 0.01
  }
}

// ---------------------------------------------------------------------------
extern "C" void kernel_launch(void* const* d_in, const int* in_sizes, int n_in,
                              void* d_out, int out_size, void* d_ws, size_t ws_size,
                              hipStream_t stream) {
  const float* data = (const float*)d_in[0];
  const int* lens = (const int*)d_in[1];
  float* out = (float*)d_out;

  float* sdtb  = (float*)d_ws;                      // 60 floats
  float* gramb = sdtb + 64;                         // 44*44 floats
  float* costb = (float*)((char*)d_ws + 8192);      // transformed cost chunks

  size_t avail = (ws_size > 8192) ? (ws_size - 8192) : 0;
  int chunk = (int)(avail / ((size_t)TSLOT * sizeof(float)));
  if (chunk < 1) chunk = 1;
  if (chunk > NBLK) chunk = NBLK;

  bool first = true;
  for (int base = 0; base < NBLK; base += chunk) {
    int n = NBLK - base;
    if (n > chunk) n = chunk;
    cost_kernel<<<dim3(4, 4, n), 256, 0, stream>>>(data, lens, costb, base);
    int extra = first ? 121 : 0;   // fuse gram onto otherwise-idle CUs
    dp_gram_kernel<<<n + extra, 256, 0, stream>>>(costb, lens, data, sdtb, gramb, base, n);
    first = false;
  }
  final_kernel<<<1, 640, 0, stream>>>(sdtb, lens, gramb, out);
}